// Round 5
// baseline (52.909 us; speedup 1.0000x reference)
//
#include <hip/hip_runtime.h>

// Volume rendering (NeRF-style) for sorted ray_id segments.
// Outputs concatenated in d_out (f32):
//   pred_rgb (R,3) | pred_depth (R,1) | bg_transmittance (R,1) | weight (N,1)

#define RPW 4  // rays per wave

struct F3 { float x, y, z; };  // align(4) so dwordx3 loads are legal anywhere

// ---- DPP helpers (VALU cross-lane, no LDS) ----
template <int CTRL, int ROW_MASK>
__device__ __forceinline__ float dpp_add(float x) {
    int t = __builtin_amdgcn_update_dpp(0, __float_as_int(x), CTRL, ROW_MASK, 0xf, true);
    return x + __int_as_float(t);
}

// wave64 inclusive prefix sum (6 VALU ops); lane 63 holds the total
__device__ __forceinline__ float wave_incl_scan(float x) {
    x = dpp_add<0x111, 0xf>(x);  // row_shr:1
    x = dpp_add<0x112, 0xf>(x);  // row_shr:2
    x = dpp_add<0x114, 0xf>(x);  // row_shr:4
    x = dpp_add<0x118, 0xf>(x);  // row_shr:8
    x = dpp_add<0x142, 0xa>(x);  // row_bcast:15 -> rows 1,3
    x = dpp_add<0x143, 0xc>(x);  // row_bcast:31 -> rows 2,3
    return x;
}

__device__ __forceinline__ float readlane_f32(float x, int lane) {
    return __int_as_float(__builtin_amdgcn_readlane(__float_as_int(x), lane));
}

__global__ void compute_starts_kernel(const int* __restrict__ ray_id,
                                      int n_samples, int n_rays,
                                      int* __restrict__ starts) {
    const int t = blockIdx.x * blockDim.x + threadIdx.x;
    const int stride = gridDim.x * blockDim.x;
    if (t == 0) {
        const int first = ray_id[0];
        for (int r = 0; r <= first; ++r) starts[r] = 0;
        const int last = ray_id[n_samples - 1];
        for (int r = last + 1; r <= n_rays; ++r) starts[r] = n_samples;
    }
    // interior boundaries, 4 samples per thread (n_samples divisible by 4)
    for (int g = t; g * 4 < n_samples; g += stride) {
        const int i4 = g * 4;
        const int4 v = *reinterpret_cast<const int4*>(ray_id + i4);
        const int prev = (i4 == 0) ? v.x : ray_id[i4 - 1];
        const int vals[5] = {prev, v.x, v.y, v.z, v.w};
        #pragma unroll
        for (int j = 0; j < 4; ++j) {
            const int p = vals[j], c = vals[j + 1];
            if (c != p) {
                for (int r = p + 1; r <= c; ++r) starts[r] = i4 + j;
            }
        }
    }
}

// One 64-sample chunk. Single-exp formulation:
//   t_i = csum + inclusive_scan(sigdt)_i ; v_i = exp(-t_i)
//   w_i = v_{i-1} - v_i   (v_{-1} = carry, injected via DPP old operand)
// Updates csum (cumsum carry) and carry (= exp(-csum) = running transmittance).
__device__ __forceinline__ void process_chunk64(
    float sg, float zv, float dtv, F3 c,
    int base, int s1, int lane, int use_exit, float texit,
    float& csum, float& carry,
    float& accR, float& accG, float& accB, float& accD,
    float* __restrict__ out_w)
{
    const int i = base + lane;
    const bool active = i < s1;
    if (use_exit && i == s1 - 1) dtv = texit - zv;   // last sample of the ray
    const float sigdt = active ? sg * dtv : 0.f;
    const float t = csum + wave_incl_scan(sigdt);
    const float v = __expf(-t);
    const int vp = __builtin_amdgcn_update_dpp(__float_as_int(carry), __float_as_int(v),
                                               0x138 /*wave_shr:1*/, 0xf, 0xf, false);
    const float w = __int_as_float(vp) - v;          // == 0 for inactive lanes
    if (active) out_w[i] = w;
    accR += w * c.x;
    accG += w * c.y;
    accB += w * c.z;
    accD += w * zv;
    csum  = readlane_f32(t, 63);
    carry = readlane_f32(v, 63);   // = exp(-csum), becomes bg after last chunk
}

__global__ __launch_bounds__(256) void render_kernel(
    const float* __restrict__ rgb,       // (N,3)
    const float* __restrict__ sigma_in,  // (N,1)
    const float* __restrict__ z_in,      // (N,)
    const float* __restrict__ dt_in,     // (N,)
    const float* __restrict__ t_exit,    // (R,1)
    const int*  __restrict__ use_exit_p, // scalar
    const int*  __restrict__ starts,     // (R+1,)
    float* __restrict__ out_rgb,         // (R,3)
    float* __restrict__ out_depth,       // (R,)
    float* __restrict__ out_bg,          // (R,)
    float* __restrict__ out_w,           // (N,)
    int n_rays, int n_samples)
{
    const int wave = threadIdx.x >> 6;
    const int lane = threadIdx.x & 63;
    const int wid  = blockIdx.x * (blockDim.x >> 6) + wave;
    const int ray0 = wid * RPW;
    if (ray0 >= n_rays) return;

    const int use_exit = *use_exit_p;
    const int imax = n_samples - 1;

    // ---- boundaries -> SGPRs (uniform) ----
    int s[RPW + 1];
    #pragma unroll
    for (int k = 0; k <= RPW; ++k) {
        s[k] = __builtin_amdgcn_readfirstlane(starts[min(ray0 + k, n_rays)]);
    }
    float texit[RPW];
    #pragma unroll
    for (int k = 0; k < RPW; ++k) {
        texit[k] = readlane_f32(t_exit[min(ray0 + k, n_rays - 1)], 0);
    }

    // ---- chunk-1 loads for all rays (pinned upfront) ----
    float sg1[RPW], z1[RPW], dt1[RPW];
    F3 c1[RPW];
    #pragma unroll
    for (int k = 0; k < RPW; ++k) {
        const int i1 = min(s[k] + lane, imax);
        sg1[k] = sigma_in[i1];
        z1[k]  = z_in[i1];
        dt1[k] = dt_in[i1];
        c1[k]  = *reinterpret_cast<const F3*>(rgb + 3 * (size_t)i1);
    }

    // ---- conditional chunk-2 loads (uniform branches = own BBs, can't sink) ----
    float sg2[RPW], z2[RPW], dt2[RPW];
    F3 c2[RPW];
    bool need2[RPW];
    #pragma unroll
    for (int k = 0; k < RPW; ++k) {
        need2[k] = (s[k] + 64) < s[k + 1];
        if (need2[k]) {
            const int i2 = min(s[k] + 64 + lane, imax);
            sg2[k] = sigma_in[i2];
            z2[k]  = z_in[i2];
            dt2[k] = dt_in[i2];
            c2[k]  = *reinterpret_cast<const F3*>(rgb + 3 * (size_t)i2);
        }
    }
    __builtin_amdgcn_sched_barrier(0);  // keep all loads issued before compute

    // ---- process rays from registers ----
    #pragma unroll
    for (int k = 0; k < RPW; ++k) {
        const int ray = ray0 + k;
        if (ray >= n_rays) break;
        const int s0 = s[k], s1 = s[k + 1];
        float csum = 0.f, carry = 1.0f;
        float accR = 0.f, accG = 0.f, accB = 0.f, accD = 0.f;

        process_chunk64(sg1[k], z1[k], dt1[k], c1[k],
                        s0, s1, lane, use_exit, texit[k],
                        csum, carry, accR, accG, accB, accD, out_w);
        if (need2[k]) {
            process_chunk64(sg2[k], z2[k], dt2[k], c2[k],
                            s0 + 64, s1, lane, use_exit, texit[k],
                            csum, carry, accR, accG, accB, accD, out_w);
        }
        // rare: rays longer than 128 samples
        for (int base = s0 + 128; base < s1; base += 64) {
            const int i = min(base + lane, imax);
            const float sg = sigma_in[i];
            const float zv = z_in[i];
            const float dtv = dt_in[i];
            const F3 cc = *reinterpret_cast<const F3*>(rgb + 3 * (size_t)i);
            process_chunk64(sg, zv, dtv, cc,
                            base, s1, lane, use_exit, texit[k],
                            csum, carry, accR, accG, accB, accD, out_w);
        }

        // per-ray reduction: inclusive scan, lane 63 holds totals
        accR = wave_incl_scan(accR);
        accG = wave_incl_scan(accG);
        accB = wave_incl_scan(accB);
        accD = wave_incl_scan(accD);
        if (lane == 63) {
            out_rgb[3 * ray + 0] = accR;
            out_rgb[3 * ray + 1] = accG;
            out_rgb[3 * ray + 2] = accB;
            out_depth[ray] = accD;
            out_bg[ray]    = carry;   // exp(-total sigdt), no exp needed
        }
    }
}

extern "C" void kernel_launch(void* const* d_in, const int* in_sizes, int n_in,
                              void* d_out, int out_size, void* d_ws, size_t ws_size,
                              hipStream_t stream) {
    const float* rgb     = (const float*)d_in[0];
    const float* sigma   = (const float*)d_in[1];
    const float* z       = (const float*)d_in[2];
    const float* dt      = (const float*)d_in[3];
    const int*   ray_id  = (const int*)d_in[4];
    const float* t_exit  = (const float*)d_in[5];
    const int*   use_ex  = (const int*)d_in[6];

    const int n_samples = in_sizes[2];   // samples_z flat count
    const int n_rays    = in_sizes[5];   // ray_t_exit flat count

    int* starts = (int*)d_ws;            // (n_rays + 1) ints

    float* out      = (float*)d_out;
    float* out_rgb  = out;
    float* out_dep  = out + (size_t)3 * n_rays;
    float* out_bg   = out + (size_t)4 * n_rays;
    float* out_w    = out + (size_t)5 * n_rays;

    compute_starts_kernel<<<2048, 256, 0, stream>>>(ray_id, n_samples, n_rays, starts);

    const int waves_per_block = 4;              // 256 threads
    const int rays_per_block  = waves_per_block * RPW;
    const int blocks = (n_rays + rays_per_block - 1) / rays_per_block;
    render_kernel<<<blocks, 256, 0, stream>>>(rgb, sigma, z, dt, t_exit, use_ex,
                                              starts, out_rgb, out_dep, out_bg,
                                              out_w, n_rays, n_samples);
}